// Round 2
// baseline (607.463 us; speedup 1.0000x reference)
//
#include <hip/hip_runtime.h>
#include <math.h>

// Problem constants (B=2,S=2048 -> T=4096 tokens)
#define T_TOK 4096
#define H_DIM 1024
#define F_DIM 4096
#define E_NUM 8
#define BK 32
#define KSPLIT 4  // ffn2 split-K factor (K=4096 -> 4 x 1024)

typedef __attribute__((ext_vector_type(8))) short bhalf8_t;
typedef __attribute__((ext_vector_type(4))) float f32x4_t;

// fp32 -> bf16 round-to-nearest-even
__device__ __forceinline__ unsigned short f2bf(float f) {
  unsigned int u = __float_as_uint(f);
  return (unsigned short)((u + 0x7fffu + ((u >> 16) & 1u)) >> 16);
}

// async global->LDS, 16B per lane. LDS dest = wave-uniform base + lane*16.
__device__ __forceinline__ void gload16(const void* g, void* l) {
  __builtin_amdgcn_global_load_lds(
      (const __attribute__((address_space(1))) unsigned int*)g,
      (__attribute__((address_space(3))) unsigned int*)l, 16, 0, 0);
}

// ---------------- kernel 0: zero the expert histogram ----------------
__global__ void k_init(int* counts) {
  if (threadIdx.x < E_NUM) counts[threadIdx.x] = 0;
}

// ---------------- kernel 0b: zero d_out (ffn2 accumulates via atomics) -----
__global__ void k_zero(float4* out) {
  out[(size_t)blockIdx.x * 256 + threadIdx.x] = (float4){0.f, 0.f, 0.f, 0.f};
}

// ---------------- kernel 1: router (fp64 accumulation to protect argmax) ---
__global__ void k_router(const float* __restrict__ x, const float* __restrict__ wr,
                         int* __restrict__ sel, float* __restrict__ wgt,
                         int* __restrict__ counts) {
  const int t = blockIdx.x;
  const int lane = threadIdx.x;  // blockDim = 64 (one wave)
  const float* xr = x + (size_t)t * H_DIM;
  double acc[E_NUM] = {0, 0, 0, 0, 0, 0, 0, 0};
  for (int h = lane; h < H_DIM; h += 64) {
    const double xv = (double)xr[h];
    const float* w = wr + (size_t)h * E_NUM;
#pragma unroll
    for (int e = 0; e < E_NUM; ++e) acc[e] += xv * (double)w[e];
  }
#pragma unroll
  for (int e = 0; e < E_NUM; ++e) {
#pragma unroll
    for (int off = 32; off > 0; off >>= 1) acc[e] += __shfl_down(acc[e], off, 64);
  }
  if (lane == 0) {
    double m = acc[0];
    int a = 0;
#pragma unroll
    for (int e = 1; e < E_NUM; ++e)
      if (acc[e] > m) { m = acc[e]; a = e; }   // strict > == first-max (jnp.argmax)
    double s = 0.0;
#pragma unroll
    for (int e = 0; e < E_NUM; ++e) s += exp(acc[e] - m);
    sel[t] = a;
    wgt[t] = (float)(1.0 / s);  // softmax prob of the argmax
    atomicAdd(&counts[a], 1);
  }
}

// ---------------- kernel 2: exclusive prefix over 8 experts ----------------
__global__ void k_prefix(const int* __restrict__ counts, int* __restrict__ offs,
                         int* __restrict__ cursors) {
  if (threadIdx.x == 0 && blockIdx.x == 0) {
    int s = 0;
    for (int e = 0; e < E_NUM; ++e) {
      offs[e] = s;
      cursors[e] = s;
      s += counts[e];
    }
    offs[E_NUM] = s;  // == T_TOK
  }
}

// ---------------- kernel 3: bucket tokens + gather x rows to bf16 ----------
__global__ void k_scatter(const float* __restrict__ x, const int* __restrict__ sel,
                          const float* __restrict__ wgt, int* __restrict__ cursors,
                          int* __restrict__ s2t, float* __restrict__ wgtS,
                          unsigned short* __restrict__ Xs) {
  const int t = blockIdx.x;  // one token per 256-thread block
  __shared__ int sslot;
  if (threadIdx.x == 0) {
    const int slot = atomicAdd(&cursors[sel[t]], 1);
    sslot = slot;
    s2t[slot] = t;
    wgtS[slot] = wgt[t];
  }
  __syncthreads();
  const int slot = sslot;
  const float4 v = reinterpret_cast<const float4*>(x + (size_t)t * H_DIM)[threadIdx.x];
  ushort4 o;
  o.x = f2bf(v.x); o.y = f2bf(v.y); o.z = f2bf(v.z); o.w = f2bf(v.w);
  reinterpret_cast<ushort4*>(Xs + (size_t)slot * H_DIM)[threadIdx.x] = o;
}

// ---------------- kernel 4: fp32 [E][K][N] -> bf16 [E][N][K] transpose -----
__global__ void k_transpose(const float* __restrict__ in, unsigned short* __restrict__ out,
                            int K, int N) {
  const int e = blockIdx.z;
  const int n0 = blockIdx.x * 64;
  const int k0 = blockIdx.y * 64;
  __shared__ float tile[64][65];  // +1 pad: conflict-free transposed reads
  const float* src = in + (size_t)e * K * N;
  unsigned short* dst = out + (size_t)e * N * K;
  const int tx = threadIdx.x & 63;
  const int ty = threadIdx.x >> 6;  // 64x4 threads, load phase
#pragma unroll
  for (int i = 0; i < 64; i += 4)
    tile[ty + i][tx] = src[(size_t)(k0 + ty + i) * N + (n0 + tx)];
  __syncthreads();
  // store phase: ushort2 per lane (4B/lane coalesced)
  const int kx = (threadIdx.x & 31) * 2;   // k pair
  const int ny = threadIdx.x >> 5;         // 0..7
#pragma unroll
  for (int i = 0; i < 64; i += 8) {
    const int n = ny + i;
    ushort2 o;
    o.x = f2bf(tile[kx][n]);
    o.y = f2bf(tile[kx + 1][n]);
    *reinterpret_cast<ushort2*>(&dst[(size_t)(n0 + n) * K + (k0 + kx)]) = o;
  }
}

// ---------------- kernel 5: FFN1  h = relu(Xs @ w1[e] + b1[e]) -------------
// A = Xs [T][H] bf16 (sorted rows), B^T = Wt [E][F][H] bf16, C = Hws [T][F] bf16
__global__ __launch_bounds__(256) void k_ffn1(const unsigned short* __restrict__ Xs,
                                              const unsigned short* __restrict__ Wt,
                                              const float* __restrict__ b1,
                                              unsigned short* __restrict__ Hws,
                                              const int* __restrict__ offs) {
  const int e = blockIdx.z;
  const int off = offs[e];
  const int cnt = offs[e + 1] - off;
  const int m0 = blockIdx.y * 128;
  if (m0 >= cnt) return;  // uniform early-exit (counts are device-side)
  const int n0 = blockIdx.x * 128;
  const int msize = cnt - m0;

  __shared__ short lA[128 * BK];
  __shared__ short lB[128 * BK];

  const int tid = threadIdx.x;
  const int lane = tid & 63;
  const int wv = tid >> 6;       // 4 waves, 2x2 over the 128x128 tile
  const int wm = (wv >> 1) * 64;
  const int wn = (wv & 1) * 64;

  // staging: 16 rows/instr, 4 lanes/row; XOR-swizzle the fetched k-chunk so
  // fragment ds_read_b128 lands 2 lanes/bank-group (free) instead of 8-way.
  const int sRow = lane >> 2;
  const int cc = lane & 3;
  const int sCol = (cc ^ ((sRow >> 1) & 3)) * 8;  // swizzled 16B chunk

  const unsigned short* Abase = Xs + (size_t)off * H_DIM;
  const unsigned short* Bbase = Wt + (size_t)e * F_DIM * H_DIM + (size_t)n0 * H_DIM;

  f32x4_t acc[4][4];
#pragma unroll
  for (int i = 0; i < 4; ++i)
#pragma unroll
    for (int j = 0; j < 4; ++j) acc[i][j] = (f32x4_t){0.f, 0.f, 0.f, 0.f};

  for (int k0 = 0; k0 < H_DIM; k0 += BK) {
    __syncthreads();
#pragma unroll
    for (int i = 0; i < 2; ++i) {
      const int g = wv * 2 + i;       // 8 groups of 16 rows
      const int row = g * 16 + sRow;  // 0..127
      int ar = row;
      if (ar >= msize) ar = 0;  // ragged tail: clamp (row 0 always valid)
      gload16(Abase + (size_t)(m0 + ar) * H_DIM + k0 + sCol, &lA[g * 16 * BK]);
      gload16(Bbase + (size_t)row * H_DIM + k0 + sCol, &lB[g * 16 * BK]);
    }
    __syncthreads();  // drains vmcnt for global_load_lds

    const int q = lane >> 4;
    const int r16 = lane & 15;
    const int sw = ((r16 >> 1) & 3);  // de-swizzle for fragment reads
    bhalf8_t af[4], bf[4];
#pragma unroll
    for (int mi = 0; mi < 4; ++mi)
      af[mi] = *reinterpret_cast<const bhalf8_t*>(&lA[(wm + mi * 16 + r16) * BK + (q ^ sw) * 8]);
#pragma unroll
    for (int ni = 0; ni < 4; ++ni)
      bf[ni] = *reinterpret_cast<const bhalf8_t*>(&lB[(wn + ni * 16 + r16) * BK + (q ^ sw) * 8]);
#pragma unroll
    for (int mi = 0; mi < 4; ++mi)
#pragma unroll
      for (int ni = 0; ni < 4; ++ni)
        acc[mi][ni] = __builtin_amdgcn_mfma_f32_16x16x32_bf16(af[mi], bf[ni], acc[mi][ni], 0, 0, 0);
  }

  // epilogue: bias + relu -> bf16.  C/D map: row = quad*4+reg, col = lane&15
  const int q = lane >> 4;
  const int c = lane & 15;
#pragma unroll
  for (int ni = 0; ni < 4; ++ni) {
    const int col = n0 + wn + ni * 16 + c;
    const float bias = b1[e * F_DIM + col];
#pragma unroll
    for (int mi = 0; mi < 4; ++mi) {
      const int rbase = wm + mi * 16 + q * 4;
#pragma unroll
      for (int r = 0; r < 4; ++r) {
        const int row = rbase + r;
        if (row < msize) {
          float v = acc[mi][ni][r] + bias;
          v = fmaxf(v, 0.0f);
          Hws[(size_t)(off + m0 + row) * F_DIM + col] = f2bf(v);
        }
      }
    }
  }
}

// ---------------- kernel 6: FFN2 split-K ----------------------------------
// out[tok] += wgt * (h @ w2[e][kslice] + (ks==0 ? b2[e] : 0))
// A = Hws [T][F] bf16, B^T = Wt [E][H][F] bf16, atomic-scatter to out fp32
__global__ __launch_bounds__(256) void k_ffn2(const unsigned short* __restrict__ Hws,
                                              const unsigned short* __restrict__ Wt,
                                              const float* __restrict__ b2,
                                              const int* __restrict__ offs,
                                              const int* __restrict__ s2t,
                                              const float* __restrict__ wgtS,
                                              float* __restrict__ out) {
  const int e = blockIdx.z >> 2;       // KSPLIT = 4
  const int ks = blockIdx.z & 3;
  const int off = offs[e];
  const int cnt = offs[e + 1] - off;
  const int m0 = blockIdx.y * 128;
  if (m0 >= cnt) return;
  const int n0 = blockIdx.x * 128;
  const int msize = cnt - m0;
  const int kbeg = ks * (F_DIM / KSPLIT);
  const int kend = kbeg + (F_DIM / KSPLIT);

  __shared__ short lA[128 * BK];
  __shared__ short lB[128 * BK];

  const int tid = threadIdx.x;
  const int lane = tid & 63;
  const int wv = tid >> 6;
  const int wm = (wv >> 1) * 64;
  const int wn = (wv & 1) * 64;

  const int sRow = lane >> 2;
  const int cc = lane & 3;
  const int sCol = (cc ^ ((sRow >> 1) & 3)) * 8;

  const unsigned short* Abase = Hws + (size_t)off * F_DIM;
  const unsigned short* Bbase = Wt + (size_t)e * H_DIM * F_DIM + (size_t)n0 * F_DIM;

  f32x4_t acc[4][4];
#pragma unroll
  for (int i = 0; i < 4; ++i)
#pragma unroll
    for (int j = 0; j < 4; ++j) acc[i][j] = (f32x4_t){0.f, 0.f, 0.f, 0.f};

  for (int k0 = kbeg; k0 < kend; k0 += BK) {
    __syncthreads();
#pragma unroll
    for (int i = 0; i < 2; ++i) {
      const int g = wv * 2 + i;
      const int row = g * 16 + sRow;
      int ar = row;
      if (ar >= msize) ar = 0;
      gload16(Abase + (size_t)(m0 + ar) * F_DIM + k0 + sCol, &lA[g * 16 * BK]);
      gload16(Bbase + (size_t)row * F_DIM + k0 + sCol, &lB[g * 16 * BK]);
    }
    __syncthreads();

    const int q = lane >> 4;
    const int r16 = lane & 15;
    const int sw = ((r16 >> 1) & 3);
    bhalf8_t af[4], bf[4];
#pragma unroll
    for (int mi = 0; mi < 4; ++mi)
      af[mi] = *reinterpret_cast<const bhalf8_t*>(&lA[(wm + mi * 16 + r16) * BK + (q ^ sw) * 8]);
#pragma unroll
    for (int ni = 0; ni < 4; ++ni)
      bf[ni] = *reinterpret_cast<const bhalf8_t*>(&lB[(wn + ni * 16 + r16) * BK + (q ^ sw) * 8]);
#pragma unroll
    for (int mi = 0; mi < 4; ++mi)
#pragma unroll
      for (int ni = 0; ni < 4; ++ni)
        acc[mi][ni] = __builtin_amdgcn_mfma_f32_16x16x32_bf16(af[mi], bf[ni], acc[mi][ni], 0, 0, 0);
  }

  // epilogue: atomic-accumulate w*(acc [+ bias if ks==0]) into out
  const int q = lane >> 4;
  const int c = lane & 15;
#pragma unroll
  for (int mi = 0; mi < 4; ++mi) {
    const int rbase = wm + mi * 16 + q * 4;
#pragma unroll
    for (int r = 0; r < 4; ++r) {
      const int row = rbase + r;
      if (row >= msize) continue;
      const int srow = off + m0 + row;
      const int tok = s2t[srow];
      const float w = wgtS[srow];
      float* orow = out + (size_t)tok * H_DIM;
#pragma unroll
      for (int ni = 0; ni < 4; ++ni) {
        const int col = n0 + wn + ni * 16 + c;
        float v = acc[mi][ni][r];
        if (ks == 0) v += b2[e * H_DIM + col];
        atomicAdd(&orow[col], w * v);
      }
    }
  }
}

extern "C" void kernel_launch(void* const* d_in, const int* in_sizes, int n_in,
                              void* d_out, int out_size, void* d_ws, size_t ws_size,
                              hipStream_t stream) {
  const float* x  = (const float*)d_in[0];   // [2,2048,1024]
  const float* wr = (const float*)d_in[1];   // [1024,8]
  const float* w1 = (const float*)d_in[2];   // [8,1024,4096]
  const float* b1 = (const float*)d_in[3];   // [8,4096]
  const float* w2 = (const float*)d_in[4];   // [8,4096,1024]
  const float* b2 = (const float*)d_in[5];   // [8,1024]
  float* out = (float*)d_out;                // [2,2048,1024]

  // Workspace layout (~109.1 MB). WT is reused: w1t for FFN1, then w2t for FFN2.
  char* ws = (char*)d_ws;
  unsigned short* WT  = (unsigned short*)(ws);                          // 64 MB
  unsigned short* XS  = (unsigned short*)(ws + 67108864);               // 8 MB
  unsigned short* HWS = (unsigned short*)(ws + 67108864 + 8388608);     // 32 MB
  char* ctrl = ws + 67108864 + 8388608 + 33554432;
  int*   sel     = (int*)(ctrl);
  int*   s2t     = (int*)(ctrl + 16384);
  float* wgt     = (float*)(ctrl + 32768);
  float* wgtS    = (float*)(ctrl + 49152);
  int*   counts  = (int*)(ctrl + 65536);
  int*   offs    = (int*)(ctrl + 65536 + 64);
  int*   cursors = (int*)(ctrl + 65536 + 128);

  k_init<<<1, 64, 0, stream>>>(counts);
  k_zero<<<T_TOK * H_DIM / (256 * 4), 256, 0, stream>>>((float4*)out);
  k_router<<<T_TOK, 64, 0, stream>>>(x, wr, sel, wgt, counts);
  k_prefix<<<1, 1, 0, stream>>>(counts, offs, cursors);
  k_scatter<<<T_TOK, 256, 0, stream>>>(x, sel, wgt, cursors, s2t, wgtS, XS);

  // w1 [E][H][F] -> WT [E][F][H]
  k_transpose<<<dim3(F_DIM / 64, H_DIM / 64, E_NUM), 256, 0, stream>>>(w1, WT, H_DIM, F_DIM);
  k_ffn1<<<dim3(F_DIM / 128, T_TOK / 128, E_NUM), 256, 0, stream>>>(XS, WT, b1, HWS, offs);

  // w2 [E][F][H] -> WT [E][H][F]
  k_transpose<<<dim3(H_DIM / 64, F_DIM / 64, E_NUM), 256, 0, stream>>>(w2, WT, F_DIM, H_DIM);
  k_ffn2<<<dim3(H_DIM / 128, T_TOK / 128, E_NUM * KSPLIT), 256, 0, stream>>>(HWS, WT, b2, offs, s2t, wgtS, out);
}

// Round 3
// 579.937 us; speedup vs baseline: 1.0475x; 1.0475x over previous
//
#include <hip/hip_runtime.h>
#include <math.h>

// Problem constants (B=2,S=2048 -> T=4096 tokens)
#define T_TOK 4096
#define H_DIM 1024
#define F_DIM 4096
#define E_NUM 8
#define BK 64  // k-tile depth (halves barrier-drain count vs 32)

typedef __attribute__((ext_vector_type(8))) short bhalf8_t;
typedef __attribute__((ext_vector_type(8))) unsigned short ushort8_t;
typedef __attribute__((ext_vector_type(4))) float f32x4_t;

// fp32 -> bf16 round-to-nearest-even
__device__ __forceinline__ unsigned short f2bf(float f) {
  unsigned int u = __float_as_uint(f);
  return (unsigned short)((u + 0x7fffu + ((u >> 16) & 1u)) >> 16);
}

// async global->LDS, 16B per lane. LDS dest = wave-uniform base + lane*16.
__device__ __forceinline__ void gload16(const void* g, void* l) {
  __builtin_amdgcn_global_load_lds(
      (const __attribute__((address_space(1))) unsigned int*)g,
      (__attribute__((address_space(3))) unsigned int*)l, 16, 0, 0);
}

// ---------------- kernel 0: zero the expert histogram ----------------
__global__ void k_init(int* counts) {
  if (threadIdx.x < E_NUM) counts[threadIdx.x] = 0;
}

// ---------------- kernel 1: router (fp64 accumulation to protect argmax) ---
// 4 waves/block, one token per wave.
__global__ __launch_bounds__(256) void k_router(const float* __restrict__ x,
                                                const float* __restrict__ wr,
                                                int* __restrict__ sel, float* __restrict__ wgt,
                                                int* __restrict__ counts) {
  const int t = blockIdx.x * 4 + (threadIdx.x >> 6);
  const int lane = threadIdx.x & 63;
  const float* xr = x + (size_t)t * H_DIM;
  double acc[E_NUM] = {0, 0, 0, 0, 0, 0, 0, 0};
  for (int h = lane; h < H_DIM; h += 64) {
    const double xv = (double)xr[h];
    const float* w = wr + (size_t)h * E_NUM;
#pragma unroll
    for (int e = 0; e < E_NUM; ++e) acc[e] += xv * (double)w[e];
  }
#pragma unroll
  for (int e = 0; e < E_NUM; ++e) {
#pragma unroll
    for (int off = 32; off > 0; off >>= 1) acc[e] += __shfl_down(acc[e], off, 64);
  }
  if (lane == 0) {
    double m = acc[0];
    int a = 0;
#pragma unroll
    for (int e = 1; e < E_NUM; ++e)
      if (acc[e] > m) { m = acc[e]; a = e; }   // strict > == first-max (jnp.argmax)
    double s = 0.0;
#pragma unroll
    for (int e = 0; e < E_NUM; ++e) s += exp(acc[e] - m);
    sel[t] = a;
    wgt[t] = (float)(1.0 / s);  // softmax prob of the argmax
    atomicAdd(&counts[a], 1);
  }
}

// ---------------- kernel 2: exclusive prefix over 8 experts ----------------
__global__ void k_prefix(const int* __restrict__ counts, int* __restrict__ offs,
                         int* __restrict__ cursors) {
  if (threadIdx.x == 0 && blockIdx.x == 0) {
    int s = 0;
    for (int e = 0; e < E_NUM; ++e) {
      offs[e] = s;
      cursors[e] = s;
      s += counts[e];
    }
    offs[E_NUM] = s;  // == T_TOK
  }
}

// ---------------- kernel 3: bucket tokens + gather x rows to bf16 ----------
__global__ void k_scatter(const float* __restrict__ x, const int* __restrict__ sel,
                          const float* __restrict__ wgt, int* __restrict__ cursors,
                          int* __restrict__ s2t, float* __restrict__ wgtS,
                          unsigned short* __restrict__ Xs) {
  const int t = blockIdx.x;  // one token per 256-thread block
  __shared__ int sslot;
  if (threadIdx.x == 0) {
    const int slot = atomicAdd(&cursors[sel[t]], 1);
    sslot = slot;
    s2t[slot] = t;
    wgtS[slot] = wgt[t];
  }
  __syncthreads();
  const int slot = sslot;
  const float4 v = reinterpret_cast<const float4*>(x + (size_t)t * H_DIM)[threadIdx.x];
  ushort4 o;
  o.x = f2bf(v.x); o.y = f2bf(v.y); o.z = f2bf(v.z); o.w = f2bf(v.w);
  reinterpret_cast<ushort4*>(Xs + (size_t)slot * H_DIM)[threadIdx.x] = o;
}

// ---------------- kernel 4: fp32 [E][K][N] -> bf16 [E][N][K] transpose -----
// 16B/lane loads (float4), 16B/lane stores (ushort8), conflict-free padded LDS.
__global__ __launch_bounds__(256) void k_transpose(const float* __restrict__ in,
                                                   unsigned short* __restrict__ out,
                                                   int K, int N) {
  const int e = blockIdx.z;
  const int n0 = blockIdx.x * 64;
  const int k0 = blockIdx.y * 64;
  __shared__ float tile[64][65];  // +1 pad
  const float* src = in + (size_t)e * K * N;
  unsigned short* dst = out + (size_t)e * N * K;
  const int l = threadIdx.x;
  const int lr = l >> 4;          // 0..15 (k-row within pass)
  const int lc = (l & 15) * 4;    // 4-col group
#pragma unroll
  for (int i = 0; i < 64; i += 16) {
    const float4 v = *reinterpret_cast<const float4*>(&src[(size_t)(k0 + lr + i) * N + n0 + lc]);
    tile[lr + i][lc] = v.x;
    tile[lr + i][lc + 1] = v.y;
    tile[lr + i][lc + 2] = v.z;
    tile[lr + i][lc + 3] = v.w;
  }
  __syncthreads();
  const int kk = (l & 7) * 8;     // 8-k group
  const int nr = l >> 3;          // 0..31 (n-row within pass)
#pragma unroll
  for (int i = 0; i < 64; i += 32) {
    const int n = nr + i;
    ushort8_t o;
#pragma unroll
    for (int j = 0; j < 8; ++j) o[j] = f2bf(tile[kk + j][n]);  // banks (kk+j+n)%32: 2-way, free
    *reinterpret_cast<ushort8_t*>(&dst[(size_t)(n0 + n) * K + k0 + kk]) = o;
  }
}

// ---------------- kernel 5: FFN1  h = relu(Xs @ w1[e] + b1[e]) -------------
// A = Xs [T][H] bf16 (sorted rows), B^T = Wt [E][F][H] bf16, C = Hws [T][F] bf16
__global__ __launch_bounds__(256, 4) void k_ffn1(const unsigned short* __restrict__ Xs,
                                                 const unsigned short* __restrict__ Wt,
                                                 const float* __restrict__ b1,
                                                 unsigned short* __restrict__ Hws,
                                                 const int* __restrict__ offs) {
  const int e = blockIdx.z;
  const int off = offs[e];
  const int cnt = offs[e + 1] - off;
  const int m0 = blockIdx.y * 128;
  if (m0 >= cnt) return;  // uniform early-exit (counts are device-side)
  const int n0 = blockIdx.x * 128;
  const int msize = cnt - m0;

  __shared__ short lA[128 * BK];
  __shared__ short lB[128 * BK];

  const int tid = threadIdx.x;
  const int lane = tid & 63;
  const int wv = tid >> 6;       // 4 waves, 2x2 over the 128x128 tile
  const int wm = (wv >> 1) * 64;
  const int wn = (wv & 1) * 64;

  // staging: 8 rows/instr, 8 lanes/row, 16B chunk each. XOR-swizzle the GLOBAL
  // chunk by the dest row (&7) so fragment ds_read_b128 is 2-way (free).
  const int sRow = lane >> 3;      // dest row within 8-row group == row&7
  const int cc = lane & 7;         // dest chunk slot
  const int gch = cc ^ sRow;       // global chunk fetched

  const unsigned short* Abase = Xs + (size_t)off * H_DIM;
  const unsigned short* Bbase = Wt + (size_t)e * F_DIM * H_DIM + (size_t)n0 * H_DIM;

  f32x4_t acc[4][4];
#pragma unroll
  for (int i = 0; i < 4; ++i)
#pragma unroll
    for (int j = 0; j < 4; ++j) acc[i][j] = (f32x4_t){0.f, 0.f, 0.f, 0.f};

  const int q = lane >> 4;
  const int r16 = lane & 15;
  const int sw = r16 & 7;  // de-swizzle for fragment reads

  for (int k0 = 0; k0 < H_DIM; k0 += BK) {
    __syncthreads();
#pragma unroll
    for (int i = 0; i < 4; ++i) {
      const int g = wv * 4 + i;       // 16 groups of 8 rows
      const int row = g * 8 + sRow;   // 0..127
      const int ar = (row < msize) ? row : 0;  // ragged tail clamp
      gload16(Abase + (size_t)(m0 + ar) * H_DIM + k0 + gch * 8, &lA[g * 8 * BK]);
      gload16(Bbase + (size_t)row * H_DIM + k0 + gch * 8, &lB[g * 8 * BK]);
    }
    __syncthreads();  // drains vmcnt for global_load_lds

#pragma unroll
    for (int step = 0; step < 2; ++step) {
      const int slot = (step * 4 + q) ^ sw;
      bhalf8_t af[4], bf[4];
#pragma unroll
      for (int mi = 0; mi < 4; ++mi)
        af[mi] = *reinterpret_cast<const bhalf8_t*>(&lA[(wm + mi * 16 + r16) * BK + slot * 8]);
#pragma unroll
      for (int ni = 0; ni < 4; ++ni)
        bf[ni] = *reinterpret_cast<const bhalf8_t*>(&lB[(wn + ni * 16 + r16) * BK + slot * 8]);
#pragma unroll
      for (int mi = 0; mi < 4; ++mi)
#pragma unroll
        for (int ni = 0; ni < 4; ++ni)
          acc[mi][ni] = __builtin_amdgcn_mfma_f32_16x16x32_bf16(af[mi], bf[ni], acc[mi][ni], 0, 0, 0);
    }
  }

  // epilogue: bias + relu -> bf16.  C/D map: row = quad*4+reg, col = lane&15
  const int c = lane & 15;
#pragma unroll
  for (int ni = 0; ni < 4; ++ni) {
    const int col = n0 + wn + ni * 16 + c;
    const float bias = b1[e * F_DIM + col];
#pragma unroll
    for (int mi = 0; mi < 4; ++mi) {
      const int rbase = wm + mi * 16 + q * 4;
#pragma unroll
      for (int r = 0; r < 4; ++r) {
        const int row = rbase + r;
        if (row < msize) {
          float v = acc[mi][ni][r] + bias;
          v = fmaxf(v, 0.0f);
          Hws[(size_t)(off + m0 + row) * F_DIM + col] = f2bf(v);
        }
      }
    }
  }
}

// ---------------- kernel 6: FFN2  out[tok] = wgt * (h @ w2[e] + b2[e]) -----
// A = Hws [T][F] bf16, B^T = Wt [E][H][F] bf16, direct scatter-store fp32.
__global__ __launch_bounds__(256, 4) void k_ffn2(const unsigned short* __restrict__ Hws,
                                                 const unsigned short* __restrict__ Wt,
                                                 const float* __restrict__ b2,
                                                 const int* __restrict__ offs,
                                                 const int* __restrict__ s2t,
                                                 const float* __restrict__ wgtS,
                                                 float* __restrict__ out) {
  const int e = blockIdx.z;
  const int off = offs[e];
  const int cnt = offs[e + 1] - off;
  const int m0 = blockIdx.y * 128;
  if (m0 >= cnt) return;
  const int n0 = blockIdx.x * 128;
  const int msize = cnt - m0;

  __shared__ short lA[128 * BK];
  __shared__ short lB[128 * BK];

  const int tid = threadIdx.x;
  const int lane = tid & 63;
  const int wv = tid >> 6;
  const int wm = (wv >> 1) * 64;
  const int wn = (wv & 1) * 64;

  const int sRow = lane >> 3;
  const int cc = lane & 7;
  const int gch = cc ^ sRow;

  const unsigned short* Abase = Hws + (size_t)off * F_DIM;
  const unsigned short* Bbase = Wt + (size_t)e * H_DIM * F_DIM + (size_t)n0 * F_DIM;

  f32x4_t acc[4][4];
#pragma unroll
  for (int i = 0; i < 4; ++i)
#pragma unroll
    for (int j = 0; j < 4; ++j) acc[i][j] = (f32x4_t){0.f, 0.f, 0.f, 0.f};

  const int q = lane >> 4;
  const int r16 = lane & 15;
  const int sw = r16 & 7;

  for (int k0 = 0; k0 < F_DIM; k0 += BK) {
    __syncthreads();
#pragma unroll
    for (int i = 0; i < 4; ++i) {
      const int g = wv * 4 + i;
      const int row = g * 8 + sRow;
      const int ar = (row < msize) ? row : 0;
      gload16(Abase + (size_t)(m0 + ar) * F_DIM + k0 + gch * 8, &lA[g * 8 * BK]);
      gload16(Bbase + (size_t)row * F_DIM + k0 + gch * 8, &lB[g * 8 * BK]);
    }
    __syncthreads();

#pragma unroll
    for (int step = 0; step < 2; ++step) {
      const int slot = (step * 4 + q) ^ sw;
      bhalf8_t af[4], bf[4];
#pragma unroll
      for (int mi = 0; mi < 4; ++mi)
        af[mi] = *reinterpret_cast<const bhalf8_t*>(&lA[(wm + mi * 16 + r16) * BK + slot * 8]);
#pragma unroll
      for (int ni = 0; ni < 4; ++ni)
        bf[ni] = *reinterpret_cast<const bhalf8_t*>(&lB[(wn + ni * 16 + r16) * BK + slot * 8]);
#pragma unroll
      for (int mi = 0; mi < 4; ++mi)
#pragma unroll
        for (int ni = 0; ni < 4; ++ni)
          acc[mi][ni] = __builtin_amdgcn_mfma_f32_16x16x32_bf16(af[mi], bf[ni], acc[mi][ni], 0, 0, 0);
    }
  }

  // epilogue: bias, routing weight, scatter to original token row (fp32)
  const int c = lane & 15;
#pragma unroll
  for (int mi = 0; mi < 4; ++mi) {
    const int rbase = wm + mi * 16 + q * 4;
#pragma unroll
    for (int r = 0; r < 4; ++r) {
      const int row = rbase + r;
      if (row >= msize) continue;
      const int srow = off + m0 + row;
      const int tok = s2t[srow];
      const float w = wgtS[srow];
      float* orow = out + (size_t)tok * H_DIM;
#pragma unroll
      for (int ni = 0; ni < 4; ++ni) {
        const int col = n0 + wn + ni * 16 + c;
        orow[col] = w * (acc[mi][ni][r] + b2[e * H_DIM + col]);
      }
    }
  }
}

extern "C" void kernel_launch(void* const* d_in, const int* in_sizes, int n_in,
                              void* d_out, int out_size, void* d_ws, size_t ws_size,
                              hipStream_t stream) {
  const float* x  = (const float*)d_in[0];   // [2,2048,1024]
  const float* wr = (const float*)d_in[1];   // [1024,8]
  const float* w1 = (const float*)d_in[2];   // [8,1024,4096]
  const float* b1 = (const float*)d_in[3];   // [8,4096]
  const float* w2 = (const float*)d_in[4];   // [8,4096,1024]
  const float* b2 = (const float*)d_in[5];   // [8,1024]
  float* out = (float*)d_out;                // [2,2048,1024]

  // Workspace layout (~109.1 MB). WT is reused: w1t for FFN1, then w2t for FFN2.
  char* ws = (char*)d_ws;
  unsigned short* WT  = (unsigned short*)(ws);                          // 64 MB
  unsigned short* XS  = (unsigned short*)(ws + 67108864);               // 8 MB
  unsigned short* HWS = (unsigned short*)(ws + 67108864 + 8388608);     // 32 MB
  char* ctrl = ws + 67108864 + 8388608 + 33554432;
  int*   sel     = (int*)(ctrl);
  int*   s2t     = (int*)(ctrl + 16384);
  float* wgt     = (float*)(ctrl + 32768);
  float* wgtS    = (float*)(ctrl + 49152);
  int*   counts  = (int*)(ctrl + 65536);
  int*   offs    = (int*)(ctrl + 65536 + 64);
  int*   cursors = (int*)(ctrl + 65536 + 128);

  k_init<<<1, 64, 0, stream>>>(counts);
  k_router<<<T_TOK / 4, 256, 0, stream>>>(x, wr, sel, wgt, counts);
  k_prefix<<<1, 1, 0, stream>>>(counts, offs, cursors);
  k_scatter<<<T_TOK, 256, 0, stream>>>(x, sel, wgt, cursors, s2t, wgtS, XS);

  // w1 [E][H][F] -> WT [E][F][H]
  k_transpose<<<dim3(F_DIM / 64, H_DIM / 64, E_NUM), 256, 0, stream>>>(w1, WT, H_DIM, F_DIM);
  k_ffn1<<<dim3(F_DIM / 128, T_TOK / 128, E_NUM), 256, 0, stream>>>(XS, WT, b1, HWS, offs);

  // w2 [E][F][H] -> WT [E][H][F]
  k_transpose<<<dim3(H_DIM / 64, F_DIM / 64, E_NUM), 256, 0, stream>>>(w2, WT, F_DIM, H_DIM);
  k_ffn2<<<dim3(H_DIM / 128, T_TOK / 128, E_NUM), 256, 0, stream>>>(HWS, WT, b2, offs, s2t, wgtS, out);
}

// Round 4
// 551.855 us; speedup vs baseline: 1.1008x; 1.0509x over previous
//
#include <hip/hip_runtime.h>
#include <math.h>

// Problem constants (B=2,S=2048 -> T=4096 tokens)
#define T_TOK 4096
#define H_DIM 1024
#define F_DIM 4096
#define E_NUM 8
#define BK 64
#define KSPLIT 4  // ffn2 split-K (needs ws >= ~176 MB; falls back to direct)

typedef __attribute__((ext_vector_type(8))) short bhalf8_t;
typedef __attribute__((ext_vector_type(8))) unsigned short ushort8_t;
typedef __attribute__((ext_vector_type(4))) float f32x4_t;

// fp32 -> bf16 round-to-nearest-even
__device__ __forceinline__ unsigned short f2bf(float f) {
  unsigned int u = __float_as_uint(f);
  return (unsigned short)((u + 0x7fffu + ((u >> 16) & 1u)) >> 16);
}

// async global->LDS, 16B per lane. LDS dest = wave-uniform base + lane*16.
__device__ __forceinline__ void gload16(const void* g, void* l) {
  __builtin_amdgcn_global_load_lds(
      (const __attribute__((address_space(1))) unsigned int*)g,
      (__attribute__((address_space(3))) unsigned int*)l, 16, 0, 0);
}

// ---------------- kernel 0: zero the expert histogram ----------------
__global__ void k_init(int* counts) {
  if (threadIdx.x < E_NUM) counts[threadIdx.x] = 0;
}

// ---------------- kernel 1: router (fp64 accumulation to protect argmax) ---
__global__ __launch_bounds__(256) void k_router(const float* __restrict__ x,
                                                const float* __restrict__ wr,
                                                int* __restrict__ sel, float* __restrict__ wgt,
                                                int* __restrict__ counts) {
  const int t = blockIdx.x * 4 + (threadIdx.x >> 6);
  const int lane = threadIdx.x & 63;
  const float* xr = x + (size_t)t * H_DIM;
  double acc[E_NUM] = {0, 0, 0, 0, 0, 0, 0, 0};
  for (int h = lane; h < H_DIM; h += 64) {
    const double xv = (double)xr[h];
    const float* w = wr + (size_t)h * E_NUM;
#pragma unroll
    for (int e = 0; e < E_NUM; ++e) acc[e] += xv * (double)w[e];
  }
#pragma unroll
  for (int e = 0; e < E_NUM; ++e) {
#pragma unroll
    for (int off = 32; off > 0; off >>= 1) acc[e] += __shfl_down(acc[e], off, 64);
  }
  if (lane == 0) {
    double m = acc[0];
    int a = 0;
#pragma unroll
    for (int e = 1; e < E_NUM; ++e)
      if (acc[e] > m) { m = acc[e]; a = e; }   // strict > == first-max (jnp.argmax)
    double s = 0.0;
#pragma unroll
    for (int e = 0; e < E_NUM; ++e) s += exp(acc[e] - m);
    sel[t] = a;
    wgt[t] = (float)(1.0 / s);  // softmax prob of the argmax
    atomicAdd(&counts[a], 1);
  }
}

// ---------------- kernel 2: exclusive prefix over 8 experts ----------------
__global__ void k_prefix(const int* __restrict__ counts, int* __restrict__ offs,
                         int* __restrict__ cursors) {
  if (threadIdx.x == 0 && blockIdx.x == 0) {
    int s = 0;
    for (int e = 0; e < E_NUM; ++e) {
      offs[e] = s;
      cursors[e] = s;
      s += counts[e];
    }
    offs[E_NUM] = s;  // == T_TOK
  }
}

// ---------------- kernel 3: bucket tokens + gather x rows to bf16 ----------
__global__ void k_scatter(const float* __restrict__ x, const int* __restrict__ sel,
                          const float* __restrict__ wgt, int* __restrict__ cursors,
                          int* __restrict__ s2t, float* __restrict__ wgtS,
                          int* __restrict__ eS, unsigned short* __restrict__ Xs) {
  const int t = blockIdx.x;  // one token per 256-thread block
  __shared__ int sslot;
  if (threadIdx.x == 0) {
    const int e = sel[t];
    const int slot = atomicAdd(&cursors[e], 1);
    sslot = slot;
    s2t[slot] = t;
    wgtS[slot] = wgt[t];
    eS[slot] = e;
  }
  __syncthreads();
  const int slot = sslot;
  const float4 v = reinterpret_cast<const float4*>(x + (size_t)t * H_DIM)[threadIdx.x];
  ushort4 o;
  o.x = f2bf(v.x); o.y = f2bf(v.y); o.z = f2bf(v.z); o.w = f2bf(v.w);
  reinterpret_cast<ushort4*>(Xs + (size_t)slot * H_DIM)[threadIdx.x] = o;
}

// ---------------- kernel 4: fp32 [E][K][N] -> bf16 [E][N][K] transpose -----
__global__ __launch_bounds__(256) void k_transpose(const float* __restrict__ in,
                                                   unsigned short* __restrict__ out,
                                                   int K, int N) {
  const int e = blockIdx.z;
  const int n0 = blockIdx.x * 64;
  const int k0 = blockIdx.y * 64;
  __shared__ float tile[64][65];  // +1 pad
  const float* src = in + (size_t)e * K * N;
  unsigned short* dst = out + (size_t)e * N * K;
  const int l = threadIdx.x;
  const int lr = l >> 4;          // 0..15 (k-row within pass)
  const int lc = (l & 15) * 4;    // 4-col group
#pragma unroll
  for (int i = 0; i < 64; i += 16) {
    const float4 v = *reinterpret_cast<const float4*>(&src[(size_t)(k0 + lr + i) * N + n0 + lc]);
    tile[lr + i][lc] = v.x;
    tile[lr + i][lc + 1] = v.y;
    tile[lr + i][lc + 2] = v.z;
    tile[lr + i][lc + 3] = v.w;
  }
  __syncthreads();
  const int kk = (l & 7) * 8;     // 8-k group
  const int nr = l >> 3;          // 0..31 (n-row within pass)
#pragma unroll
  for (int i = 0; i < 64; i += 32) {
    const int n = nr + i;
    ushort8_t o;
#pragma unroll
    for (int j = 0; j < 8; ++j) o[j] = f2bf(tile[kk + j][n]);
    *reinterpret_cast<ushort8_t*>(&dst[(size_t)(n0 + n) * K + k0 + kk]) = o;
  }
}

// ---------------- kernel 5: FFN1  h = relu(Xs @ w1[e] + b1[e]) -------------
// 128m x 64n tile (2048 active blocks -> 8/CU for latency hiding).
// A = Xs [T][H] bf16 (sorted rows), B^T = Wt [E][F][H] bf16, C = Hws [T][F] bf16
__global__ __launch_bounds__(256, 4) void k_ffn1(const unsigned short* __restrict__ Xs,
                                                 const unsigned short* __restrict__ Wt,
                                                 const float* __restrict__ b1,
                                                 unsigned short* __restrict__ Hws,
                                                 const int* __restrict__ offs) {
  const int e = blockIdx.z;
  const int off = offs[e];
  const int cnt = offs[e + 1] - off;
  const int m0 = blockIdx.y * 128;
  if (m0 >= cnt) return;  // uniform early-exit
  const int n0 = blockIdx.x * 64;
  const int msize = cnt - m0;

  __shared__ short lA[128 * BK];  // 16 KB
  __shared__ short lB[64 * BK];   // 8 KB

  const int tid = threadIdx.x;
  const int lane = tid & 63;
  const int wv = tid >> 6;         // 4 waves, 2x2 over 128x64
  const int wm = (wv >> 1) * 64;
  const int wn = (wv & 1) * 32;

  // staging: 8 rows/instr, 8 lanes/row, 16B chunk. XOR-swizzle the GLOBAL
  // chunk by dest row (&7) -> fragment ds_read_b128 measured conflict-free.
  const int sRow = lane >> 3;
  const int cc = lane & 7;
  const int gch = cc ^ sRow;

  const unsigned short* Abase = Xs + (size_t)off * H_DIM;
  const unsigned short* Bbase = Wt + (size_t)e * F_DIM * H_DIM + (size_t)n0 * H_DIM;

  f32x4_t acc[4][2];
#pragma unroll
  for (int i = 0; i < 4; ++i)
#pragma unroll
    for (int j = 0; j < 2; ++j) acc[i][j] = (f32x4_t){0.f, 0.f, 0.f, 0.f};

  const int q = lane >> 4;
  const int r16 = lane & 15;
  const int sw = r16 & 7;  // de-swizzle for fragment reads

  for (int k0 = 0; k0 < H_DIM; k0 += BK) {
    __syncthreads();
#pragma unroll
    for (int i = 0; i < 4; ++i) {  // lA: 16 groups of 8 rows
      const int g = wv * 4 + i;
      const int row = g * 8 + sRow;
      const int ar = (row < msize) ? row : 0;
      gload16(Abase + (size_t)(m0 + ar) * H_DIM + k0 + gch * 8, &lA[g * 8 * BK]);
    }
#pragma unroll
    for (int i = 0; i < 2; ++i) {  // lB: 8 groups of 8 rows
      const int g = wv * 2 + i;
      const int row = g * 8 + sRow;
      gload16(Bbase + (size_t)row * H_DIM + k0 + gch * 8, &lB[g * 8 * BK]);
    }
    __syncthreads();  // drains vmcnt for global_load_lds

#pragma unroll
    for (int step = 0; step < 2; ++step) {
      const int slot = (step * 4 + q) ^ sw;
      bhalf8_t af[4], bf[2];
#pragma unroll
      for (int mi = 0; mi < 4; ++mi)
        af[mi] = *reinterpret_cast<const bhalf8_t*>(&lA[(wm + mi * 16 + r16) * BK + slot * 8]);
#pragma unroll
      for (int ni = 0; ni < 2; ++ni)
        bf[ni] = *reinterpret_cast<const bhalf8_t*>(&lB[(wn + ni * 16 + r16) * BK + slot * 8]);
#pragma unroll
      for (int mi = 0; mi < 4; ++mi)
#pragma unroll
        for (int ni = 0; ni < 2; ++ni)
          acc[mi][ni] = __builtin_amdgcn_mfma_f32_16x16x32_bf16(af[mi], bf[ni], acc[mi][ni], 0, 0, 0);
    }
  }

  // epilogue: bias + relu -> bf16.  C/D map: row = quad*4+reg, col = lane&15
  const int c = lane & 15;
#pragma unroll
  for (int ni = 0; ni < 2; ++ni) {
    const int col = n0 + wn + ni * 16 + c;
    const float bias = b1[e * F_DIM + col];
#pragma unroll
    for (int mi = 0; mi < 4; ++mi) {
      const int rbase = wm + mi * 16 + q * 4;
#pragma unroll
      for (int r = 0; r < 4; ++r) {
        const int row = rbase + r;
        if (row < msize) {
          float v = acc[mi][ni][r] + bias;
          v = fmaxf(v, 0.0f);
          Hws[(size_t)(off + m0 + row) * F_DIM + col] = f2bf(v);
        }
      }
    }
  }
}

// ---------------- kernel 6a: FFN2 split-K main -----------------------------
// Partial sums (no bias/weight) stored coalesced to P[ks][srow][h] fp32.
__global__ __launch_bounds__(256, 4) void k_ffn2_sk(const unsigned short* __restrict__ Hws,
                                                    const unsigned short* __restrict__ Wt,
                                                    const int* __restrict__ offs,
                                                    float* __restrict__ P) {
  const int e = blockIdx.z >> 2;  // KSPLIT = 4
  const int ks = blockIdx.z & 3;
  const int off = offs[e];
  const int cnt = offs[e + 1] - off;
  const int m0 = blockIdx.y * 128;
  if (m0 >= cnt) return;
  const int n0 = blockIdx.x * 128;
  const int msize = cnt - m0;
  const int kbeg = ks * (F_DIM / KSPLIT);
  const int kend = kbeg + (F_DIM / KSPLIT);

  __shared__ short lA[128 * BK];
  __shared__ short lB[128 * BK];

  const int tid = threadIdx.x;
  const int lane = tid & 63;
  const int wv = tid >> 6;
  const int wm = (wv >> 1) * 64;
  const int wn = (wv & 1) * 64;

  const int sRow = lane >> 3;
  const int cc = lane & 7;
  const int gch = cc ^ sRow;

  const unsigned short* Abase = Hws + (size_t)off * F_DIM;
  const unsigned short* Bbase = Wt + (size_t)e * H_DIM * F_DIM + (size_t)n0 * F_DIM;

  f32x4_t acc[4][4];
#pragma unroll
  for (int i = 0; i < 4; ++i)
#pragma unroll
    for (int j = 0; j < 4; ++j) acc[i][j] = (f32x4_t){0.f, 0.f, 0.f, 0.f};

  const int q = lane >> 4;
  const int r16 = lane & 15;
  const int sw = r16 & 7;

  for (int k0 = kbeg; k0 < kend; k0 += BK) {
    __syncthreads();
#pragma unroll
    for (int i = 0; i < 4; ++i) {
      const int g = wv * 4 + i;
      const int row = g * 8 + sRow;
      const int ar = (row < msize) ? row : 0;
      gload16(Abase + (size_t)(m0 + ar) * F_DIM + k0 + gch * 8, &lA[g * 8 * BK]);
      gload16(Bbase + (size_t)row * F_DIM + k0 + gch * 8, &lB[g * 8 * BK]);
    }
    __syncthreads();

#pragma unroll
    for (int step = 0; step < 2; ++step) {
      const int slot = (step * 4 + q) ^ sw;
      bhalf8_t af[4], bf[4];
#pragma unroll
      for (int mi = 0; mi < 4; ++mi)
        af[mi] = *reinterpret_cast<const bhalf8_t*>(&lA[(wm + mi * 16 + r16) * BK + slot * 8]);
#pragma unroll
      for (int ni = 0; ni < 4; ++ni)
        bf[ni] = *reinterpret_cast<const bhalf8_t*>(&lB[(wn + ni * 16 + r16) * BK + slot * 8]);
#pragma unroll
      for (int mi = 0; mi < 4; ++mi)
#pragma unroll
        for (int ni = 0; ni < 4; ++ni)
          acc[mi][ni] = __builtin_amdgcn_mfma_f32_16x16x32_bf16(af[mi], bf[ni], acc[mi][ni], 0, 0, 0);
    }
  }

  // epilogue: raw partial sums, coalesced (sorted row order, no scatter here)
  const int c = lane & 15;
  float* Pb = P + (size_t)ks * T_TOK * H_DIM;
#pragma unroll
  for (int mi = 0; mi < 4; ++mi) {
    const int rbase = wm + mi * 16 + q * 4;
#pragma unroll
    for (int r = 0; r < 4; ++r) {
      const int row = rbase + r;
      if (row >= msize) continue;
      float* prow = Pb + (size_t)(off + m0 + row) * H_DIM;
#pragma unroll
      for (int ni = 0; ni < 4; ++ni) prow[n0 + wn + ni * 16 + c] = acc[mi][ni][r];
    }
  }
}

// ---------------- kernel 6b: split-K reduce + bias + weight + scatter ------
__global__ __launch_bounds__(256) void k_reduce(const float* __restrict__ P,
                                                const float* __restrict__ b2,
                                                const int* __restrict__ s2t,
                                                const int* __restrict__ eS,
                                                const float* __restrict__ wgtS,
                                                float* __restrict__ out) {
  const int srow = blockIdx.x;
  const int tok = s2t[srow];
  const int e = eS[srow];
  const float w = wgtS[srow];
  const int i = threadIdx.x;  // 256 threads x float4 = 1024 = H
  const size_t rowoff = (size_t)srow * H_DIM / 4 + i;
  const float4 p0 = reinterpret_cast<const float4*>(P)[rowoff];
  const float4 p1 = reinterpret_cast<const float4*>(P + (size_t)T_TOK * H_DIM)[rowoff];
  const float4 p2 = reinterpret_cast<const float4*>(P + (size_t)2 * T_TOK * H_DIM)[rowoff];
  const float4 p3 = reinterpret_cast<const float4*>(P + (size_t)3 * T_TOK * H_DIM)[rowoff];
  const float4 b = reinterpret_cast<const float4*>(b2 + (size_t)e * H_DIM)[i];
  float4 o;
  o.x = w * (p0.x + p1.x + p2.x + p3.x + b.x);
  o.y = w * (p0.y + p1.y + p2.y + p3.y + b.y);
  o.z = w * (p0.z + p1.z + p2.z + p3.z + b.z);
  o.w = w * (p0.w + p1.w + p2.w + p3.w + b.w);
  reinterpret_cast<float4*>(out + (size_t)tok * H_DIM)[i] = o;
}

// ---------------- kernel 6c: FFN2 direct (fallback if ws too small) --------
__global__ __launch_bounds__(256, 4) void k_ffn2_direct(const unsigned short* __restrict__ Hws,
                                                        const unsigned short* __restrict__ Wt,
                                                        const float* __restrict__ b2,
                                                        const int* __restrict__ offs,
                                                        const int* __restrict__ s2t,
                                                        const float* __restrict__ wgtS,
                                                        float* __restrict__ out) {
  const int e = blockIdx.z;
  const int off = offs[e];
  const int cnt = offs[e + 1] - off;
  const int m0 = blockIdx.y * 128;
  if (m0 >= cnt) return;
  const int n0 = blockIdx.x * 128;
  const int msize = cnt - m0;

  __shared__ short lA[128 * BK];
  __shared__ short lB[128 * BK];

  const int tid = threadIdx.x;
  const int lane = tid & 63;
  const int wv = tid >> 6;
  const int wm = (wv >> 1) * 64;
  const int wn = (wv & 1) * 64;

  const int sRow = lane >> 3;
  const int cc = lane & 7;
  const int gch = cc ^ sRow;

  const unsigned short* Abase = Hws + (size_t)off * F_DIM;
  const unsigned short* Bbase = Wt + (size_t)e * H_DIM * F_DIM + (size_t)n0 * F_DIM;

  f32x4_t acc[4][4];
#pragma unroll
  for (int i = 0; i < 4; ++i)
#pragma unroll
    for (int j = 0; j < 4; ++j) acc[i][j] = (f32x4_t){0.f, 0.f, 0.f, 0.f};

  const int q = lane >> 4;
  const int r16 = lane & 15;
  const int sw = r16 & 7;

  for (int k0 = 0; k0 < F_DIM; k0 += BK) {
    __syncthreads();
#pragma unroll
    for (int i = 0; i < 4; ++i) {
      const int g = wv * 4 + i;
      const int row = g * 8 + sRow;
      const int ar = (row < msize) ? row : 0;
      gload16(Abase + (size_t)(m0 + ar) * F_DIM + k0 + gch * 8, &lA[g * 8 * BK]);
      gload16(Bbase + (size_t)row * F_DIM + k0 + gch * 8, &lB[g * 8 * BK]);
    }
    __syncthreads();

#pragma unroll
    for (int step = 0; step < 2; ++step) {
      const int slot = (step * 4 + q) ^ sw;
      bhalf8_t af[4], bf[4];
#pragma unroll
      for (int mi = 0; mi < 4; ++mi)
        af[mi] = *reinterpret_cast<const bhalf8_t*>(&lA[(wm + mi * 16 + r16) * BK + slot * 8]);
#pragma unroll
      for (int ni = 0; ni < 4; ++ni)
        bf[ni] = *reinterpret_cast<const bhalf8_t*>(&lB[(wn + ni * 16 + r16) * BK + slot * 8]);
#pragma unroll
      for (int mi = 0; mi < 4; ++mi)
#pragma unroll
        for (int ni = 0; ni < 4; ++ni)
          acc[mi][ni] = __builtin_amdgcn_mfma_f32_16x16x32_bf16(af[mi], bf[ni], acc[mi][ni], 0, 0, 0);
    }
  }

  const int c = lane & 15;
#pragma unroll
  for (int mi = 0; mi < 4; ++mi) {
    const int rbase = wm + mi * 16 + q * 4;
#pragma unroll
    for (int r = 0; r < 4; ++r) {
      const int row = rbase + r;
      if (row >= msize) continue;
      const int srow = off + m0 + row;
      const int tok = s2t[srow];
      const float w = wgtS[srow];
      float* orow = out + (size_t)tok * H_DIM;
#pragma unroll
      for (int ni = 0; ni < 4; ++ni) {
        const int col = n0 + wn + ni * 16 + c;
        orow[col] = w * (acc[mi][ni][r] + b2[e * H_DIM + col]);
      }
    }
  }
}

extern "C" void kernel_launch(void* const* d_in, const int* in_sizes, int n_in,
                              void* d_out, int out_size, void* d_ws, size_t ws_size,
                              hipStream_t stream) {
  const float* x  = (const float*)d_in[0];   // [2,2048,1024]
  const float* wr = (const float*)d_in[1];   // [1024,8]
  const float* w1 = (const float*)d_in[2];   // [8,1024,4096]
  const float* b1 = (const float*)d_in[3];   // [8,4096]
  const float* w2 = (const float*)d_in[4];   // [8,4096,1024]
  const float* b2 = (const float*)d_in[5];   // [8,1024]
  float* out = (float*)d_out;                // [2,2048,1024]

  // Workspace layout: WT 64MB | XS 8MB | HWS 32MB | ctrl 96KB | P 64MB
  char* ws = (char*)d_ws;
  unsigned short* WT  = (unsigned short*)(ws);
  unsigned short* XS  = (unsigned short*)(ws + 67108864);
  unsigned short* HWS = (unsigned short*)(ws + 67108864 + 8388608);
  char* ctrl = ws + 109051904;
  int*   sel     = (int*)(ctrl);
  int*   s2t     = (int*)(ctrl + 16384);
  float* wgt     = (float*)(ctrl + 32768);
  float* wgtS    = (float*)(ctrl + 49152);
  int*   eS      = (int*)(ctrl + 65536);
  int*   counts  = (int*)(ctrl + 81920);
  int*   offs    = (int*)(ctrl + 81920 + 64);
  int*   cursors = (int*)(ctrl + 81920 + 128);
  float* P = (float*)(ws + 109150208);       // 64 MB (split-K partials)
  const bool use_splitk = ws_size >= (size_t)(109150208) + (size_t)KSPLIT * T_TOK * H_DIM * 4;

  k_init<<<1, 64, 0, stream>>>(counts);
  k_router<<<T_TOK / 4, 256, 0, stream>>>(x, wr, sel, wgt, counts);
  k_prefix<<<1, 1, 0, stream>>>(counts, offs, cursors);
  k_scatter<<<T_TOK, 256, 0, stream>>>(x, sel, wgt, cursors, s2t, wgtS, eS, XS);

  // w1 [E][H][F] -> WT [E][F][H]
  k_transpose<<<dim3(F_DIM / 64, H_DIM / 64, E_NUM), 256, 0, stream>>>(w1, WT, H_DIM, F_DIM);
  k_ffn1<<<dim3(F_DIM / 64, T_TOK / 128, E_NUM), 256, 0, stream>>>(XS, WT, b1, HWS, offs);

  // w2 [E][F][H] -> WT [E][H][F]
  k_transpose<<<dim3(H_DIM / 64, F_DIM / 64, E_NUM), 256, 0, stream>>>(w2, WT, F_DIM, H_DIM);
  if (use_splitk) {
    k_ffn2_sk<<<dim3(H_DIM / 128, T_TOK / 128, E_NUM * KSPLIT), 256, 0, stream>>>(HWS, WT, offs, P);
    k_reduce<<<T_TOK, 256, 0, stream>>>(P, b2, s2t, eS, wgtS, out);
  } else {
    k_ffn2_direct<<<dim3(H_DIM / 128, T_TOK / 128, E_NUM), 256, 0, stream>>>(HWS, WT, b2, offs, s2t, wgtS, out);
  }
}